// Round 2
// baseline (59788.617 us; speedup 1.0000x reference)
//
#include <hip/hip_runtime.h>
#include <math.h>

#define QQ 512
#define NN 1000
#define HHID 1024
#define CCON 128
#define G4 4000
#define NBLK 250   // persistent-layer grid: 250 blocks x 256 thr, 4 n per block

__device__ inline float wred_min(float v){ for(int o=32;o;o>>=1) v=fminf(v,__shfl_xor(v,o)); return v; }
__device__ inline float wred_max(float v){ for(int o=32;o;o>>=1) v=fmaxf(v,__shfl_xor(v,o)); return v; }
__device__ inline float wred_sum(float v){ for(int o=32;o;o>>=1) v+=__shfl_xor(v,o); return v; }

// C[M,R] = A[M,K] @ B[R,K]^T + bias1[r] + bias2[r]
__global__ __launch_bounds__(256) void gemm_nt(
    const float* __restrict__ A, const float* __restrict__ B,
    const float* __restrict__ bias1, const float* __restrict__ bias2,
    float* __restrict__ C, int M, int K, int R) {
  __shared__ float As[16][65];
  __shared__ float Bs[16][65];
  int tid = threadIdx.x;
  int tx = tid & 15, ty = tid >> 4;
  int m0 = blockIdx.y * 64, r0 = blockIdx.x * 64;
  float acc[4][4] = {};
  for (int k0 = 0; k0 < K; k0 += 16) {
#pragma unroll
    for (int i = 0; i < 4; i++) {
      int idx = tid + 256 * i;
      int ml = idx >> 4, kl = idx & 15;
      int m = m0 + ml, k = k0 + kl;
      As[kl][ml] = (m < M && k < K) ? A[(size_t)m * K + k] : 0.f;
      int r = r0 + ml;
      Bs[kl][ml] = (r < R && k < K) ? B[(size_t)r * K + k] : 0.f;
    }
    __syncthreads();
#pragma unroll
    for (int kk = 0; kk < 16; kk++) {
      float a[4], b[4];
#pragma unroll
      for (int i = 0; i < 4; i++) a[i] = As[kk][ty * 4 + i];
#pragma unroll
      for (int j = 0; j < 4; j++) b[j] = Bs[kk][tx * 4 + j];
#pragma unroll
      for (int i = 0; i < 4; i++)
#pragma unroll
        for (int j = 0; j < 4; j++) acc[i][j] += a[i] * b[j];
    }
    __syncthreads();
  }
#pragma unroll
  for (int i = 0; i < 4; i++) {
    int m = m0 + ty * 4 + i;
    if (m >= M) continue;
#pragma unroll
    for (int j = 0; j < 4; j++) {
      int r = r0 + tx * 4 + j;
      if (r >= R) continue;
      float v = acc[i][j];
      if (bias1) v += bias1[r];
      if (bias2) v += bias2[r];
      C[(size_t)m * R + r] = v;
    }
  }
}

// Persistent per-layer LSTM recurrence: all 512 timesteps in one launch.
// 250 blocks x 256 threads; wave w of block b owns neuron n = b*4 + w and
// holds its 4 W_hh rows in 64 VGPRs. Cross-block handoff of h[t] via
// agent-scope release/acquire flags (per-XCD L2s are non-coherent).
__global__ __launch_bounds__(256) void lstm_layer(
    const float* __restrict__ P,    // [QQ, G4] input-side gates (bias incl.)
    const float* __restrict__ Whh,  // [G4, NN]
    float* __restrict__ Hall,       // [QQ, NN] this layer's h trajectory
    int* __restrict__ flags) {      // [QQ, 256] zeroed before launch
  __shared__ float hs[1024];
  int tid = threadIdx.x;
  int wave = tid >> 6, lane = tid & 63;
  int n = blockIdx.x * 4 + wave;

  // Preload W_hh rows into registers: wreg[q][it] = Whh[q*1000+n][it*64+lane]
  float wreg[4][16];
#pragma unroll
  for (int q = 0; q < 4; q++) {
    const float* wrow = Whh + (size_t)(q * NN + n) * NN;
#pragma unroll
    for (int it = 0; it < 16; it++) {
      int k = it * 64 + lane;
      wreg[q][it] = (k < NN) ? wrow[k] : 0.f;
    }
  }
  // Zero LDS pad (k = 1000..1023) so the unguarded dot loop is safe.
  if (tid >= 232 && tid < 256) hs[768 + tid] = 0.f;  // 1000..1023
  __syncthreads();

  float creg = 0.f;  // cell state for neuron n, lives in a register all 512 steps

  for (int t = 0; t < QQ; t++) {
    float g[4];
    if (t == 0) {
#pragma unroll
      for (int q = 0; q < 4; q++) g[q] = P[(size_t)q * NN + n];
    } else {
      // Wait until all 250 blocks published h[t-1].
      for (;;) {
        int ok = 1;
        for (int i = tid; i < NBLK; i += 256)
          ok &= (__hip_atomic_load(&flags[(t - 1) * 256 + i], __ATOMIC_RELAXED,
                                   __HIP_MEMORY_SCOPE_AGENT) != 0);
        if (__syncthreads_and(ok)) break;
        __builtin_amdgcn_s_sleep(1);
      }
      __builtin_amdgcn_fence(__ATOMIC_ACQUIRE, "agent");
      // Broadcast h[t-1] into LDS (agent-scope loads bypass stale L1/L2).
      for (int i = tid; i < NN; i += 256)
        hs[i] = __hip_atomic_load(&Hall[(size_t)(t - 1) * NN + i],
                                  __ATOMIC_RELAXED, __HIP_MEMORY_SCOPE_AGENT);
      __syncthreads();
      float acc0 = 0.f, acc1 = 0.f, acc2 = 0.f, acc3 = 0.f;
#pragma unroll
      for (int it = 0; it < 16; it++) {
        float hv = hs[it * 64 + lane];
        acc0 += wreg[0][it] * hv;
        acc1 += wreg[1][it] * hv;
        acc2 += wreg[2][it] * hv;
        acc3 += wreg[3][it] * hv;
      }
#pragma unroll
      for (int o = 32; o; o >>= 1) {
        acc0 += __shfl_xor(acc0, o);
        acc1 += __shfl_xor(acc1, o);
        acc2 += __shfl_xor(acc2, o);
        acc3 += __shfl_xor(acc3, o);
      }
      const float* pt = P + (size_t)t * G4;
      g[0] = acc0 + pt[n];
      g[1] = acc1 + pt[NN + n];
      g[2] = acc2 + pt[2 * NN + n];
      g[3] = acc3 + pt[3 * NN + n];
    }
    // Activations (all lanes hold identical sums after the butterfly).
    float ii = 1.f / (1.f + expf(-g[0]));
    float ff = 1.f / (1.f + expf(-g[1]));
    float gg = tanhf(g[2]);
    float oo = 1.f / (1.f + expf(-g[3]));
    creg = ff * creg + ii * gg;
    float h = oo * tanhf(creg);
    if (lane == 0)
      __hip_atomic_store(&Hall[(size_t)t * NN + n], h, __ATOMIC_RELAXED,
                         __HIP_MEMORY_SCOPE_AGENT);
    __syncthreads();  // drains all 4 waves' stores (vmcnt(0) before barrier)
    if (tid == 0)
      __hip_atomic_store(&flags[t * 256 + blockIdx.x], 1, __ATOMIC_RELEASE,
                         __HIP_MEMORY_SCOPE_AGENT);
  }
}

// Per-timestep output: min/max normalize + floored exp IRF. One block per t.
__global__ __launch_bounds__(256) void epilogue_out(
    const float* __restrict__ H7,   // [QQ, NN]
    const float* __restrict__ Wlin, const float* __restrict__ blin,
    const int* __restrict__ ccol, const float* __restrict__ Dnz,
    float* __restrict__ out,        // [QQ, NN]
    float* __restrict__ irbuf, float* __restrict__ mnirbuf) {
  int t = blockIdx.x, tid = threadIdx.x;
  int wave = tid >> 6, lane = tid & 63;
  __shared__ float hbuf[NN];
  __shared__ float smin[4], smax[4];
  __shared__ float bc[2];
  float lmin = 3.4e38f, lmax = -3.4e38f;
  for (int i = tid; i < NN; i += 256) {
    float v = H7[(size_t)t * NN + i];
    hbuf[i] = v;
    lmin = fminf(lmin, v); lmax = fmaxf(lmax, v);
  }
  lmin = wred_min(lmin); lmax = wred_max(lmax);
  if (lane == 0) { smin[wave] = lmin; smax[wave] = lmax; }
  __syncthreads();
  if (tid == 0) {
    bc[0] = fminf(fminf(smin[0], smin[1]), fminf(smin[2], smin[3]));
    bc[1] = fmaxf(fmaxf(smax[0], smax[1]), fmaxf(smax[2], smax[3]));
  }
  __syncthreads();
  float hmn = bc[0], hmx = bc[1];
  float clo = 3.4e38f, chi = -3.4e38f;
  if (tid < CCON) {
    float w = Wlin[tid], b = blin[tid];
    clo = b + fminf(w * hmn, w * hmx);
    chi = b + fmaxf(w * hmn, w * hmx);
  }
  clo = wred_min(clo); chi = wred_max(chi);
  __syncthreads();  // smin/smax reused below
  if (lane == 0) { smin[wave] = clo; smax[wave] = chi; }
  __syncthreads();
  if (tid == 0) {
    float mn = fminf(fminf(smin[0], smin[1]), fminf(smin[2], smin[3]));
    float mx = fmaxf(fmaxf(smax[0], smax[1]), fmaxf(smax[2], smax[3]));
    float ir = 1.f / (mx - mn);
    bc[0] = mn; bc[1] = ir;
    irbuf[t] = ir;
    mnirbuf[t] = mn * ir;
  }
  __syncthreads();
  float mn = bc[0], ir = bc[1];
  int cc = ccol[t];
  float wcc = Wlin[cc], bcc = blin[cc], d = Dnz[t];
  for (int n = tid; n < NN; n += 256) {
    float s = (hbuf[n] * wcc + bcc - mn) * ir;
    out[(size_t)t * NN + n] = fmaxf(0.25f, 1.f - expf(-10.f * (s - d)));
  }
}

__global__ void reduce_scalars(const float* __restrict__ ir,
                               const float* __restrict__ mnir,
                               float* __restrict__ scal) {
  int tid = threadIdx.x;  // 512
  int wave = tid >> 6, lane = tid & 63;
  __shared__ float s1[8], s2[8];
  float a = ir[tid], b = mnir[tid];
  a = wred_sum(a); b = wred_sum(b);
  if (lane == 0) { s1[wave] = a; s2[wave] = b; }
  __syncthreads();
  if (tid == 0) {
    float A = 0.f, B = 0.f;
    for (int i = 0; i < 8; i++) { A += s1[i]; B += s2[i]; }
    scal[0] = A; scal[1] = B;
  }
}

__global__ void accum_A(const float* __restrict__ H7,
                        const float* __restrict__ ir,
                        float* __restrict__ Avec) {
  int n = blockIdx.x * 256 + threadIdx.x;
  if (n < NN) {
    float acc = 0.f;
    for (int t = 0; t < QQ; t++) acc += H7[(size_t)t * NN + n] * ir[t];
    Avec[n] = acc;
  }
}

__global__ void skills_out(const float* __restrict__ Avec,
                           const float* __restrict__ Wlin,
                           const float* __restrict__ blin,
                           const float* __restrict__ scal,
                           float* __restrict__ out) {  // [NN, CCON]
  int idx = blockIdx.x * 256 + threadIdx.x;
  if (idx < NN * CCON) {
    int n = idx >> 7, c = idx & 127;
    out[idx] = (Wlin[c] * Avec[n] + blin[c] * scal[0] - scal[1]) * (1.f / (float)QQ);
  }
}

extern "C" void kernel_launch(void* const* d_in, const int* in_sizes, int n_in,
                              void* d_out, int out_size, void* d_ws, size_t ws_size,
                              hipStream_t stream) {
  const float* inputs = (const float*)d_in[0];
  const int*   ccol   = (const int*)d_in[1];
  const float* W_inp  = (const float*)d_in[2];
  const float* b_inp  = (const float*)d_in[3];
  const float* W_ih0  = (const float*)d_in[4];
  const float* W_hh0  = (const float*)d_in[5];
  const float* b_ih0  = (const float*)d_in[6];
  const float* b_hh0  = (const float*)d_in[7];
  const float* W_ih   = (const float*)d_in[8];   // [7, 4000, 1000]
  const float* W_hh   = (const float*)d_in[9];   // [7, 4000, 1000]
  const float* b_ih   = (const float*)d_in[10];  // [7, 4000]
  const float* b_hh   = (const float*)d_in[11];  // [7, 4000]
  const float* W_lin  = (const float*)d_in[12];  // [128]
  const float* b_lin  = (const float*)d_in[13];  // [128]
  const float* D_nz   = (const float*)d_in[14];  // [512]

  float* ws = (float*)d_ws;
  float* X    = ws;                       // [512,1024]
  float* P    = X + (size_t)QQ * HHID;    // [512,4000]
  float* H0   = P + (size_t)QQ * G4;      // [512,1000]
  float* H1   = H0 + (size_t)QQ * NN;     // [512,1000]
  float* irb  = H1 + (size_t)QQ * NN;     // [512]
  float* mnir = irb + QQ;                 // [512]
  float* Avec = mnir + QQ;                // [1024]
  float* scal = Avec + 1024;              // [2]
  int*   flags = (int*)(scal + 16);       // [512*256] ints

  float* out_main   = (float*)d_out;            // [512,1000]
  float* out_skills = (float*)d_out + QQ * NN;  // [1000,128]

  // X = inputs @ W_inp^T + b_inp   (M=512, K=1000, R=1024)
  gemm_nt<<<dim3(HHID / 64, QQ / 64), 256, 0, stream>>>(
      inputs, W_inp, b_inp, nullptr, X, QQ, NN, HHID);
  // P0 = X @ W_ih0^T + b_ih0 + b_hh0   (M=512, K=1024, R=4000)
  gemm_nt<<<dim3((G4 + 63) / 64, QQ / 64), 256, 0, stream>>>(
      X, W_ih0, b_ih0, b_hh0, P, QQ, HHID, G4);
  hipMemsetAsync(flags, 0, QQ * 256 * sizeof(int), stream);
  lstm_layer<<<NBLK, 256, 0, stream>>>(P, W_hh0, H0, flags);

  for (int l = 1; l < 8; l++) {
    float* Hprev = ((l - 1) & 1) ? H1 : H0;
    float* Hcur  = (l & 1) ? H1 : H0;
    const float* wih = W_ih + (size_t)(l - 1) * G4 * NN;
    const float* whh = W_hh + (size_t)(l - 1) * G4 * NN;
    gemm_nt<<<dim3((G4 + 63) / 64, QQ / 64), 256, 0, stream>>>(
        Hprev, wih, b_ih + (size_t)(l - 1) * G4, b_hh + (size_t)(l - 1) * G4,
        P, QQ, NN, G4);
    hipMemsetAsync(flags, 0, QQ * 256 * sizeof(int), stream);
    lstm_layer<<<NBLK, 256, 0, stream>>>(P, whh, Hcur, flags);
  }
  float* H7 = H1;  // layer 7 writes H1

  epilogue_out<<<QQ, 256, 0, stream>>>(H7, W_lin, b_lin, ccol, D_nz,
                                       out_main, irb, mnir);
  reduce_scalars<<<1, 512, 0, stream>>>(irb, mnir, scal);
  accum_A<<<4, 256, 0, stream>>>(H7, irb, Avec);
  skills_out<<<(NN * CCON) / 256, 256, 0, stream>>>(Avec, W_lin, b_lin, scal,
                                                    out_skills);
}

// Round 3
// 53300.751 us; speedup vs baseline: 1.1217x; 1.1217x over previous
//
#include <hip/hip_runtime.h>
#include <math.h>

#define QQ 512
#define NN 1000
#define HHID 1024
#define CCON 128
#define G4 4000
#define LBLK 63     // ceil(1000/16) persistent blocks, 1024 thr, 1 neuron/wave

__device__ inline float wred_min(float v){ for(int o=32;o;o>>=1) v=fminf(v,__shfl_xor(v,o)); return v; }
__device__ inline float wred_max(float v){ for(int o=32;o;o>>=1) v=fmaxf(v,__shfl_xor(v,o)); return v; }
__device__ inline float wred_sum(float v){ for(int o=32;o;o>>=1) v+=__shfl_xor(v,o); return v; }

// C[M,R] = A[M,K] @ B[R,K]^T + bias1[r] + bias2[r]
__global__ __launch_bounds__(256) void gemm_nt(
    const float* __restrict__ A, const float* __restrict__ B,
    const float* __restrict__ bias1, const float* __restrict__ bias2,
    float* __restrict__ C, int M, int K, int R) {
  __shared__ float As[16][65];
  __shared__ float Bs[16][65];
  int tid = threadIdx.x;
  int tx = tid & 15, ty = tid >> 4;
  int m0 = blockIdx.y * 64, r0 = blockIdx.x * 64;
  float acc[4][4] = {};
  for (int k0 = 0; k0 < K; k0 += 16) {
#pragma unroll
    for (int i = 0; i < 4; i++) {
      int idx = tid + 256 * i;
      int ml = idx >> 4, kl = idx & 15;
      int m = m0 + ml, k = k0 + kl;
      As[kl][ml] = (m < M && k < K) ? A[(size_t)m * K + k] : 0.f;
      int r = r0 + ml;
      Bs[kl][ml] = (r < R && k < K) ? B[(size_t)r * K + k] : 0.f;
    }
    __syncthreads();
#pragma unroll
    for (int kk = 0; kk < 16; kk++) {
      float a[4], b[4];
#pragma unroll
      for (int i = 0; i < 4; i++) a[i] = As[kk][ty * 4 + i];
#pragma unroll
      for (int j = 0; j < 4; j++) b[j] = Bs[kk][tx * 4 + j];
#pragma unroll
      for (int i = 0; i < 4; i++)
#pragma unroll
        for (int j = 0; j < 4; j++) acc[i][j] += a[i] * b[j];
    }
    __syncthreads();
  }
#pragma unroll
  for (int i = 0; i < 4; i++) {
    int m = m0 + ty * 4 + i;
    if (m >= M) continue;
#pragma unroll
    for (int j = 0; j < 4; j++) {
      int r = r0 + tx * 4 + j;
      if (r >= R) continue;
      float v = acc[i][j];
      if (bias1) v += bias1[r];
      if (bias2) v += bias2[r];
      C[(size_t)m * R + r] = v;
    }
  }
}

// Persistent per-layer LSTM recurrence: all 512 timesteps in one launch.
// 63 blocks x 1024 threads; wave w owns neuron n = blockIdx*16 + w, holding
// its 4 W_hh rows in 64 VGPRs. Cross-block handoff via monotonic stamped
// flags (flag[b] = t+1 after h[t] published), agent scope (LLC-coherent).
__global__ __launch_bounds__(1024, 4) void lstm_layer(
    const float* __restrict__ P,    // [QQ, G4] input-side gates (bias incl.)
    const float* __restrict__ Whh,  // [G4, NN]
    float* __restrict__ Hall,       // [QQ, NN] this layer's h trajectory
    int* __restrict__ flag) {       // [64] zeroed at launch start
  __shared__ float hs[1024];
  int tid = threadIdx.x;
  int wave = tid >> 6, lane = tid & 63;
  int n = blockIdx.x * 16 + wave;
  bool active = (n < NN);

  // Preload W_hh rows: wreg[q][it] = Whh[q*1000+n][it*64+lane]
  float wreg[4][16];
  if (active) {
#pragma unroll
    for (int q = 0; q < 4; q++) {
      const float* wrow = Whh + (size_t)(q * NN + n) * NN;
#pragma unroll
      for (int it = 0; it < 16; it++) {
        int k = it * 64 + lane;
        wreg[q][it] = (k < NN) ? wrow[k] : 0.f;
      }
    }
  } else {
#pragma unroll
    for (int q = 0; q < 4; q++)
#pragma unroll
      for (int it = 0; it < 16; it++) wreg[q][it] = 0.f;
  }
  if (tid >= NN) hs[tid] = 0.f;  // zero pad 1000..1023 once

  float creg = 0.f;  // cell state for neuron n, register-resident all 512 steps

  for (int t = 0; t < QQ; t++) {
    if (t > 0) {
      // Wait until all 63 blocks published h[t-1] (flag >= t).
      for (;;) {
        int ok = 1;
        if (tid < LBLK)
          ok = (__hip_atomic_load(&flag[tid], __ATOMIC_RELAXED,
                                  __HIP_MEMORY_SCOPE_AGENT) >= t);
        if (__syncthreads_and(ok)) break;
        __builtin_amdgcn_s_sleep(2);
      }
      __builtin_amdgcn_fence(__ATOMIC_ACQUIRE, "agent");
      if (tid < NN)
        hs[tid] = __hip_atomic_load(&Hall[(size_t)(t - 1) * NN + tid],
                                    __ATOMIC_RELAXED, __HIP_MEMORY_SCOPE_AGENT);
      __syncthreads();
    }
    if (active) {
      const float* pt = P + (size_t)t * G4;
      float g0, g1, g2, g3;
      if (t == 0) {
        g0 = pt[n]; g1 = pt[NN + n]; g2 = pt[2 * NN + n]; g3 = pt[3 * NN + n];
      } else {
        float a0 = 0.f, a1 = 0.f, a2 = 0.f, a3 = 0.f;
#pragma unroll
        for (int it = 0; it < 16; it++) {
          float hv = hs[it * 64 + lane];
          a0 += wreg[0][it] * hv;
          a1 += wreg[1][it] * hv;
          a2 += wreg[2][it] * hv;
          a3 += wreg[3][it] * hv;
        }
#pragma unroll
        for (int o = 32; o; o >>= 1) {
          a0 += __shfl_xor(a0, o);
          a1 += __shfl_xor(a1, o);
          a2 += __shfl_xor(a2, o);
          a3 += __shfl_xor(a3, o);
        }
        g0 = a0 + pt[n]; g1 = a1 + pt[NN + n];
        g2 = a2 + pt[2 * NN + n]; g3 = a3 + pt[3 * NN + n];
      }
      float ii = 1.f / (1.f + expf(-g0));
      float ff = 1.f / (1.f + expf(-g1));
      float gg = tanhf(g2);
      float oo = 1.f / (1.f + expf(-g3));
      creg = ff * creg + ii * gg;
      float h = oo * tanhf(creg);
      if (lane == 0)
        __hip_atomic_store(&Hall[(size_t)t * NN + n], h, __ATOMIC_RELAXED,
                           __HIP_MEMORY_SCOPE_AGENT);
    }
    __syncthreads();  // all waves' h stores drained (vmcnt(0) before barrier)
    if (tid == 0)
      __hip_atomic_store(&flag[blockIdx.x], t + 1, __ATOMIC_RELEASE,
                         __HIP_MEMORY_SCOPE_AGENT);
  }
}

// Per-timestep output: min/max normalize + floored exp IRF. One block per t.
__global__ __launch_bounds__(256) void epilogue_out(
    const float* __restrict__ H7,   // [QQ, NN]
    const float* __restrict__ Wlin, const float* __restrict__ blin,
    const int* __restrict__ ccol, const float* __restrict__ Dnz,
    float* __restrict__ out,        // [QQ, NN]
    float* __restrict__ irbuf, float* __restrict__ mnirbuf) {
  int t = blockIdx.x, tid = threadIdx.x;
  int wave = tid >> 6, lane = tid & 63;
  __shared__ float hbuf[NN];
  __shared__ float smin[4], smax[4];
  __shared__ float bc[2];
  float lmin = 3.4e38f, lmax = -3.4e38f;
  for (int i = tid; i < NN; i += 256) {
    float v = H7[(size_t)t * NN + i];
    hbuf[i] = v;
    lmin = fminf(lmin, v); lmax = fmaxf(lmax, v);
  }
  lmin = wred_min(lmin); lmax = wred_max(lmax);
  if (lane == 0) { smin[wave] = lmin; smax[wave] = lmax; }
  __syncthreads();
  if (tid == 0) {
    bc[0] = fminf(fminf(smin[0], smin[1]), fminf(smin[2], smin[3]));
    bc[1] = fmaxf(fmaxf(smax[0], smax[1]), fmaxf(smax[2], smax[3]));
  }
  __syncthreads();
  float hmn = bc[0], hmx = bc[1];
  float clo = 3.4e38f, chi = -3.4e38f;
  if (tid < CCON) {
    float w = Wlin[tid], b = blin[tid];
    clo = b + fminf(w * hmn, w * hmx);
    chi = b + fmaxf(w * hmn, w * hmx);
  }
  clo = wred_min(clo); chi = wred_max(chi);
  __syncthreads();  // smin/smax reused below
  if (lane == 0) { smin[wave] = clo; smax[wave] = chi; }
  __syncthreads();
  if (tid == 0) {
    float mn = fminf(fminf(smin[0], smin[1]), fminf(smin[2], smin[3]));
    float mx = fmaxf(fmaxf(smax[0], smax[1]), fmaxf(smax[2], smax[3]));
    float ir = 1.f / (mx - mn);
    bc[0] = mn; bc[1] = ir;
    irbuf[t] = ir;
    mnirbuf[t] = mn * ir;
  }
  __syncthreads();
  float mn = bc[0], ir = bc[1];
  int cc = ccol[t];
  float wcc = Wlin[cc], bcc = blin[cc], d = Dnz[t];
  for (int n = tid; n < NN; n += 256) {
    float s = (hbuf[n] * wcc + bcc - mn) * ir;
    out[(size_t)t * NN + n] = fmaxf(0.25f, 1.f - expf(-10.f * (s - d)));
  }
}

__global__ void reduce_scalars(const float* __restrict__ ir,
                               const float* __restrict__ mnir,
                               float* __restrict__ scal) {
  int tid = threadIdx.x;  // 512
  int wave = tid >> 6, lane = tid & 63;
  __shared__ float s1[8], s2[8];
  float a = ir[tid], b = mnir[tid];
  a = wred_sum(a); b = wred_sum(b);
  if (lane == 0) { s1[wave] = a; s2[wave] = b; }
  __syncthreads();
  if (tid == 0) {
    float A = 0.f, B = 0.f;
    for (int i = 0; i < 8; i++) { A += s1[i]; B += s2[i]; }
    scal[0] = A; scal[1] = B;
  }
}

__global__ void accum_A(const float* __restrict__ H7,
                        const float* __restrict__ ir,
                        float* __restrict__ Avec) {
  int n = blockIdx.x * 256 + threadIdx.x;
  if (n < NN) {
    float acc = 0.f;
    for (int t = 0; t < QQ; t++) acc += H7[(size_t)t * NN + n] * ir[t];
    Avec[n] = acc;
  }
}

__global__ void skills_out(const float* __restrict__ Avec,
                           const float* __restrict__ Wlin,
                           const float* __restrict__ blin,
                           const float* __restrict__ scal,
                           float* __restrict__ out) {  // [NN, CCON]
  int idx = blockIdx.x * 256 + threadIdx.x;
  if (idx < NN * CCON) {
    int n = idx >> 7, c = idx & 127;
    out[idx] = (Wlin[c] * Avec[n] + blin[c] * scal[0] - scal[1]) * (1.f / (float)QQ);
  }
}

extern "C" void kernel_launch(void* const* d_in, const int* in_sizes, int n_in,
                              void* d_out, int out_size, void* d_ws, size_t ws_size,
                              hipStream_t stream) {
  const float* inputs = (const float*)d_in[0];
  const int*   ccol   = (const int*)d_in[1];
  const float* W_inp  = (const float*)d_in[2];
  const float* b_inp  = (const float*)d_in[3];
  const float* W_ih0  = (const float*)d_in[4];
  const float* W_hh0  = (const float*)d_in[5];
  const float* b_ih0  = (const float*)d_in[6];
  const float* b_hh0  = (const float*)d_in[7];
  const float* W_ih   = (const float*)d_in[8];   // [7, 4000, 1000]
  const float* W_hh   = (const float*)d_in[9];   // [7, 4000, 1000]
  const float* b_ih   = (const float*)d_in[10];  // [7, 4000]
  const float* b_hh   = (const float*)d_in[11];  // [7, 4000]
  const float* W_lin  = (const float*)d_in[12];  // [128]
  const float* b_lin  = (const float*)d_in[13];  // [128]
  const float* D_nz   = (const float*)d_in[14];  // [512]

  float* ws = (float*)d_ws;
  float* X    = ws;                       // [512,1024]
  float* P    = X + (size_t)QQ * HHID;    // [512,4000]
  float* H0   = P + (size_t)QQ * G4;      // [512,1000]
  float* H1   = H0 + (size_t)QQ * NN;     // [512,1000]
  float* irb  = H1 + (size_t)QQ * NN;     // [512]
  float* mnir = irb + QQ;                 // [512]
  float* Avec = mnir + QQ;                // [1024]
  float* scal = Avec + 1024;              // [2]
  int*   flags = (int*)(scal + 16);       // [8][64] per-layer stamped flags

  float* out_main   = (float*)d_out;            // [512,1000]
  float* out_skills = (float*)d_out + QQ * NN;  // [1000,128]

  // One small memset per launch (part of the captured graph): all layer flags.
  hipMemsetAsync(flags, 0, 8 * 64 * sizeof(int), stream);

  // X = inputs @ W_inp^T + b_inp   (M=512, K=1000, R=1024)
  gemm_nt<<<dim3(HHID / 64, QQ / 64), 256, 0, stream>>>(
      inputs, W_inp, b_inp, nullptr, X, QQ, NN, HHID);
  // P0 = X @ W_ih0^T + b_ih0 + b_hh0   (M=512, K=1024, R=4000)
  gemm_nt<<<dim3((G4 + 63) / 64, QQ / 64), 256, 0, stream>>>(
      X, W_ih0, b_ih0, b_hh0, P, QQ, HHID, G4);
  lstm_layer<<<LBLK, 1024, 0, stream>>>(P, W_hh0, H0, flags);

  for (int l = 1; l < 8; l++) {
    float* Hprev = ((l - 1) & 1) ? H1 : H0;
    float* Hcur  = (l & 1) ? H1 : H0;
    const float* wih = W_ih + (size_t)(l - 1) * G4 * NN;
    const float* whh = W_hh + (size_t)(l - 1) * G4 * NN;
    gemm_nt<<<dim3((G4 + 63) / 64, QQ / 64), 256, 0, stream>>>(
        Hprev, wih, b_ih + (size_t)(l - 1) * G4, b_hh + (size_t)(l - 1) * G4,
        P, QQ, NN, G4);
    lstm_layer<<<LBLK, 1024, 0, stream>>>(P, whh, Hcur, flags + l * 64);
  }
  float* H7 = H1;  // layer 7 writes H1

  epilogue_out<<<QQ, 256, 0, stream>>>(H7, W_lin, b_lin, ccol, D_nz,
                                       out_main, irb, mnir);
  reduce_scalars<<<1, 512, 0, stream>>>(irb, mnir, scal);
  accum_A<<<4, 256, 0, stream>>>(H7, irb, Avec);
  skills_out<<<(NN * CCON) / 256, 256, 0, stream>>>(Avec, W_lin, b_lin, scal,
                                                    out_skills);
}

// Round 4
// 17116.371 us; speedup vs baseline: 3.4931x; 3.1140x over previous
//
#include <hip/hip_runtime.h>
#include <math.h>

#define QQ 512
#define NN 1000
#define HHID 1024
#define CCON 128
#define G4 4000
#define LBLK 63     // ceil(1000/16) persistent blocks, 1024 thr, 1 neuron/wave

__device__ inline float wred_min(float v){ for(int o=32;o;o>>=1) v=fminf(v,__shfl_xor(v,o)); return v; }
__device__ inline float wred_max(float v){ for(int o=32;o;o>>=1) v=fmaxf(v,__shfl_xor(v,o)); return v; }
__device__ inline float wred_sum(float v){ for(int o=32;o;o>>=1) v+=__shfl_xor(v,o); return v; }

// C[M,R] = A[M,K] @ B[R,K]^T + bias1[r] + bias2[r]
__global__ __launch_bounds__(256) void gemm_nt(
    const float* __restrict__ A, const float* __restrict__ B,
    const float* __restrict__ bias1, const float* __restrict__ bias2,
    float* __restrict__ C, int M, int K, int R) {
  __shared__ float As[16][65];
  __shared__ float Bs[16][65];
  int tid = threadIdx.x;
  int tx = tid & 15, ty = tid >> 4;
  int m0 = blockIdx.y * 64, r0 = blockIdx.x * 64;
  float acc[4][4] = {};
  for (int k0 = 0; k0 < K; k0 += 16) {
#pragma unroll
    for (int i = 0; i < 4; i++) {
      int idx = tid + 256 * i;
      int ml = idx >> 4, kl = idx & 15;
      int m = m0 + ml, k = k0 + kl;
      As[kl][ml] = (m < M && k < K) ? A[(size_t)m * K + k] : 0.f;
      int r = r0 + ml;
      Bs[kl][ml] = (r < R && k < K) ? B[(size_t)r * K + k] : 0.f;
    }
    __syncthreads();
#pragma unroll
    for (int kk = 0; kk < 16; kk++) {
      float a[4], b[4];
#pragma unroll
      for (int i = 0; i < 4; i++) a[i] = As[kk][ty * 4 + i];
#pragma unroll
      for (int j = 0; j < 4; j++) b[j] = Bs[kk][tx * 4 + j];
#pragma unroll
      for (int i = 0; i < 4; i++)
#pragma unroll
        for (int j = 0; j < 4; j++) acc[i][j] += a[i] * b[j];
    }
    __syncthreads();
  }
#pragma unroll
  for (int i = 0; i < 4; i++) {
    int m = m0 + ty * 4 + i;
    if (m >= M) continue;
#pragma unroll
    for (int j = 0; j < 4; j++) {
      int r = r0 + tx * 4 + j;
      if (r >= R) continue;
      float v = acc[i][j];
      if (bias1) v += bias1[r];
      if (bias2) v += bias2[r];
      C[(size_t)m * R + r] = v;
    }
  }
}

// Persistent per-layer LSTM recurrence: all 512 timesteps in one launch.
// 63 blocks x 1024 threads; wave w owns neuron n = blockIdx*16 + w, holding
// its 4 W_hh rows in 64 VGPRs. Cross-block handoff of h[t] via relaxed
// agent-scope atomics only (sc1 -> coherent at LLC, NO fences: an agent
// acquire fence emits buffer_inv = full L2 invalidate each step, ~10us).
// Completion is signalled by a per-timestep counter: each block adds 1 after
// __syncthreads() has drained its h stores; readers poll ctr[t-1] == 63.
__global__ __launch_bounds__(1024, 4) void lstm_layer(
    const float* __restrict__ P,    // [QQ, G4] input-side gates (bias incl.)
    const float* __restrict__ Whh,  // [G4, NN]
    float* __restrict__ Hall,       // [QQ, NN] this layer's h trajectory
    int* __restrict__ ctr) {        // [QQ] zeroed before launch
  __shared__ float hs[1024];
  int tid = threadIdx.x;
  int wave = tid >> 6, lane = tid & 63;
  int n = blockIdx.x * 16 + wave;
  bool active = (n < NN);

  // Preload W_hh rows: wreg[q][it] = Whh[q*1000+n][it*64+lane]
  float wreg[4][16];
  if (active) {
#pragma unroll
    for (int q = 0; q < 4; q++) {
      const float* wrow = Whh + (size_t)(q * NN + n) * NN;
#pragma unroll
      for (int it = 0; it < 16; it++) {
        int k = it * 64 + lane;
        wreg[q][it] = (k < NN) ? wrow[k] : 0.f;
      }
    }
  } else {
#pragma unroll
    for (int q = 0; q < 4; q++)
#pragma unroll
      for (int it = 0; it < 16; it++) wreg[q][it] = 0.f;
  }
  if (tid >= NN) hs[tid] = 0.f;  // zero pad 1000..1023 once

  float creg = 0.f;  // cell state, register-resident for all 512 steps

  for (int t = 0; t < QQ; t++) {
    if (t > 0) {
      // Wait until all 63 blocks published h[t-1] (single hot line).
      for (;;) {
        int ok = 1;
        if (tid < 64)  // one wave polls; 64 lanes same addr -> 1 line request
          ok = (__hip_atomic_load(&ctr[t - 1], __ATOMIC_RELAXED,
                                  __HIP_MEMORY_SCOPE_AGENT) >= LBLK);
        if (__syncthreads_and(ok)) break;
        __builtin_amdgcn_s_sleep(2);
      }
      if (tid < NN)
        hs[tid] = __hip_atomic_load(&Hall[(size_t)(t - 1) * NN + tid],
                                    __ATOMIC_RELAXED, __HIP_MEMORY_SCOPE_AGENT);
      __syncthreads();
    }
    if (active) {
      const float* pt = P + (size_t)t * G4;
      float g0, g1, g2, g3;
      if (t == 0) {
        g0 = pt[n]; g1 = pt[NN + n]; g2 = pt[2 * NN + n]; g3 = pt[3 * NN + n];
      } else {
        float a0 = 0.f, a1 = 0.f, a2 = 0.f, a3 = 0.f;
#pragma unroll
        for (int it = 0; it < 16; it++) {
          float hv = hs[it * 64 + lane];
          a0 += wreg[0][it] * hv;
          a1 += wreg[1][it] * hv;
          a2 += wreg[2][it] * hv;
          a3 += wreg[3][it] * hv;
        }
#pragma unroll
        for (int o = 32; o; o >>= 1) {
          a0 += __shfl_xor(a0, o);
          a1 += __shfl_xor(a1, o);
          a2 += __shfl_xor(a2, o);
          a3 += __shfl_xor(a3, o);
        }
        g0 = a0 + pt[n]; g1 = a1 + pt[NN + n];
        g2 = a2 + pt[2 * NN + n]; g3 = a3 + pt[3 * NN + n];
      }
      float ii = 1.f / (1.f + expf(-g0));
      float ff = 1.f / (1.f + expf(-g1));
      float gg = tanhf(g2);
      float oo = 1.f / (1.f + expf(-g3));
      creg = ff * creg + ii * gg;
      float h = oo * tanhf(creg);
      if (lane == 0)
        __hip_atomic_store(&Hall[(size_t)t * NN + n], h, __ATOMIC_RELAXED,
                           __HIP_MEMORY_SCOPE_AGENT);
    }
    __syncthreads();  // compiler drains vmcnt(0) before s_barrier -> h at LLC
    if (tid == 0)
      __hip_atomic_fetch_add(&ctr[t], 1, __ATOMIC_RELAXED,
                             __HIP_MEMORY_SCOPE_AGENT);
  }
}

// Per-timestep output: min/max normalize + floored exp IRF. One block per t.
__global__ __launch_bounds__(256) void epilogue_out(
    const float* __restrict__ H7,   // [QQ, NN]
    const float* __restrict__ Wlin, const float* __restrict__ blin,
    const int* __restrict__ ccol, const float* __restrict__ Dnz,
    float* __restrict__ out,        // [QQ, NN]
    float* __restrict__ irbuf, float* __restrict__ mnirbuf) {
  int t = blockIdx.x, tid = threadIdx.x;
  int wave = tid >> 6, lane = tid & 63;
  __shared__ float hbuf[NN];
  __shared__ float smin[4], smax[4];
  __shared__ float bc[2];
  float lmin = 3.4e38f, lmax = -3.4e38f;
  for (int i = tid; i < NN; i += 256) {
    float v = H7[(size_t)t * NN + i];
    hbuf[i] = v;
    lmin = fminf(lmin, v); lmax = fmaxf(lmax, v);
  }
  lmin = wred_min(lmin); lmax = wred_max(lmax);
  if (lane == 0) { smin[wave] = lmin; smax[wave] = lmax; }
  __syncthreads();
  if (tid == 0) {
    bc[0] = fminf(fminf(smin[0], smin[1]), fminf(smin[2], smin[3]));
    bc[1] = fmaxf(fmaxf(smax[0], smax[1]), fmaxf(smax[2], smax[3]));
  }
  __syncthreads();
  float hmn = bc[0], hmx = bc[1];
  float clo = 3.4e38f, chi = -3.4e38f;
  if (tid < CCON) {
    float w = Wlin[tid], b = blin[tid];
    clo = b + fminf(w * hmn, w * hmx);
    chi = b + fmaxf(w * hmn, w * hmx);
  }
  clo = wred_min(clo); chi = wred_max(chi);
  __syncthreads();  // smin/smax reused below
  if (lane == 0) { smin[wave] = clo; smax[wave] = chi; }
  __syncthreads();
  if (tid == 0) {
    float mn = fminf(fminf(smin[0], smin[1]), fminf(smin[2], smin[3]));
    float mx = fmaxf(fmaxf(smax[0], smax[1]), fmaxf(smax[2], smax[3]));
    float ir = 1.f / (mx - mn);
    bc[0] = mn; bc[1] = ir;
    irbuf[t] = ir;
    mnirbuf[t] = mn * ir;
  }
  __syncthreads();
  float mn = bc[0], ir = bc[1];
  int cc = ccol[t];
  float wcc = Wlin[cc], bcc = blin[cc], d = Dnz[t];
  for (int n = tid; n < NN; n += 256) {
    float s = (hbuf[n] * wcc + bcc - mn) * ir;
    out[(size_t)t * NN + n] = fmaxf(0.25f, 1.f - expf(-10.f * (s - d)));
  }
}

__global__ void reduce_scalars(const float* __restrict__ ir,
                               const float* __restrict__ mnir,
                               float* __restrict__ scal) {
  int tid = threadIdx.x;  // 512
  int wave = tid >> 6, lane = tid & 63;
  __shared__ float s1[8], s2[8];
  float a = ir[tid], b = mnir[tid];
  a = wred_sum(a); b = wred_sum(b);
  if (lane == 0) { s1[wave] = a; s2[wave] = b; }
  __syncthreads();
  if (tid == 0) {
    float A = 0.f, B = 0.f;
    for (int i = 0; i < 8; i++) { A += s1[i]; B += s2[i]; }
    scal[0] = A; scal[1] = B;
  }
}

__global__ void accum_A(const float* __restrict__ H7,
                        const float* __restrict__ ir,
                        float* __restrict__ Avec) {
  int n = blockIdx.x * 256 + threadIdx.x;
  if (n < NN) {
    float acc = 0.f;
    for (int t = 0; t < QQ; t++) acc += H7[(size_t)t * NN + n] * ir[t];
    Avec[n] = acc;
  }
}

__global__ void skills_out(const float* __restrict__ Avec,
                           const float* __restrict__ Wlin,
                           const float* __restrict__ blin,
                           const float* __restrict__ scal,
                           float* __restrict__ out) {  // [NN, CCON]
  int idx = blockIdx.x * 256 + threadIdx.x;
  if (idx < NN * CCON) {
    int n = idx >> 7, c = idx & 127;
    out[idx] = (Wlin[c] * Avec[n] + blin[c] * scal[0] - scal[1]) * (1.f / (float)QQ);
  }
}

extern "C" void kernel_launch(void* const* d_in, const int* in_sizes, int n_in,
                              void* d_out, int out_size, void* d_ws, size_t ws_size,
                              hipStream_t stream) {
  const float* inputs = (const float*)d_in[0];
  const int*   ccol   = (const int*)d_in[1];
  const float* W_inp  = (const float*)d_in[2];
  const float* b_inp  = (const float*)d_in[3];
  const float* W_ih0  = (const float*)d_in[4];
  const float* W_hh0  = (const float*)d_in[5];
  const float* b_ih0  = (const float*)d_in[6];
  const float* b_hh0  = (const float*)d_in[7];
  const float* W_ih   = (const float*)d_in[8];   // [7, 4000, 1000]
  const float* W_hh   = (const float*)d_in[9];   // [7, 4000, 1000]
  const float* b_ih   = (const float*)d_in[10];  // [7, 4000]
  const float* b_hh   = (const float*)d_in[11];  // [7, 4000]
  const float* W_lin  = (const float*)d_in[12];  // [128]
  const float* b_lin  = (const float*)d_in[13];  // [128]
  const float* D_nz   = (const float*)d_in[14];  // [512]

  float* ws = (float*)d_ws;
  float* X    = ws;                       // [512,1024]
  float* P    = X + (size_t)QQ * HHID;    // [512,4000]
  float* H0   = P + (size_t)QQ * G4;      // [512,1000]
  float* H1   = H0 + (size_t)QQ * NN;     // [512,1000]
  float* irb  = H1 + (size_t)QQ * NN;     // [512]
  float* mnir = irb + QQ;                 // [512]
  float* Avec = mnir + QQ;                // [1024]
  float* scal = Avec + 1024;              // [2]
  int*   ctrs = (int*)(scal + 16);        // [8][QQ] per-layer step counters

  float* out_main   = (float*)d_out;            // [512,1000]
  float* out_skills = (float*)d_out + QQ * NN;  // [1000,128]

  // One small memset per launch (captured in the graph): all layer counters.
  hipMemsetAsync(ctrs, 0, 8 * QQ * sizeof(int), stream);

  // X = inputs @ W_inp^T + b_inp   (M=512, K=1000, R=1024)
  gemm_nt<<<dim3(HHID / 64, QQ / 64), 256, 0, stream>>>(
      inputs, W_inp, b_inp, nullptr, X, QQ, NN, HHID);
  // P0 = X @ W_ih0^T + b_ih0 + b_hh0   (M=512, K=1024, R=4000)
  gemm_nt<<<dim3((G4 + 63) / 64, QQ / 64), 256, 0, stream>>>(
      X, W_ih0, b_ih0, b_hh0, P, QQ, HHID, G4);
  lstm_layer<<<LBLK, 1024, 0, stream>>>(P, W_hh0, H0, ctrs);

  for (int l = 1; l < 8; l++) {
    float* Hprev = ((l - 1) & 1) ? H1 : H0;
    float* Hcur  = (l & 1) ? H1 : H0;
    const float* wih = W_ih + (size_t)(l - 1) * G4 * NN;
    const float* whh = W_hh + (size_t)(l - 1) * G4 * NN;
    gemm_nt<<<dim3((G4 + 63) / 64, QQ / 64), 256, 0, stream>>>(
        Hprev, wih, b_ih + (size_t)(l - 1) * G4, b_hh + (size_t)(l - 1) * G4,
        P, QQ, NN, G4);
    lstm_layer<<<LBLK, 1024, 0, stream>>>(P, whh, Hcur, ctrs + l * QQ);
  }
  float* H7 = H1;  // layer 7 writes H1

  epilogue_out<<<QQ, 256, 0, stream>>>(H7, W_lin, b_lin, ccol, D_nz,
                                       out_main, irb, mnir);
  reduce_scalars<<<1, 512, 0, stream>>>(irb, mnir, scal);
  accum_A<<<4, 256, 0, stream>>>(H7, irb, Avec);
  skills_out<<<(NN * CCON) / 256, 256, 0, stream>>>(Avec, W_lin, b_lin, scal,
                                                    out_skills);
}